// Round 14
// baseline (558.168 us; speedup 1.0000x reference)
//
#include <hip/hip_runtime.h>
#include <math.h>

// ---------------------------------------------------------------------------
// Model_24180665876772  Round 14: revert mgemm to R12's proven 8-wave 32x64
// (R13's 4-wave m97 tile halved waves/CU: occ 51->26%, FFN1 63.8->65.9).
// New: end-of-layer decomp emits the transposed state directly (kills the
// layer-1 trans_bb, ~10us).
// ---------------------------------------------------------------------------

typedef unsigned short ushort_t;
typedef unsigned int uint_t;
using bf16x8_t = __attribute__((ext_vector_type(8))) short;
using f32x4_t  = __attribute__((ext_vector_type(4))) float;
using u16x8_t  = __attribute__((ext_vector_type(8))) unsigned short;

__device__ __forceinline__ unsigned short f2b(float x) {
    union { float f; uint_t u; } c; c.f = x;
    uint_t r = c.u + 0x7fffu + ((c.u >> 16) & 1u);   // RNE
    return (unsigned short)(r >> 16);
}
__device__ __forceinline__ float b2f(unsigned short h) {
    union { uint_t u; float f; } c; c.u = ((uint_t)h) << 16; return c.f;
}
// tanh-form GELU via sigmoid: gelu(x) ~= x * sigmoid(1.59577x + 0.0713548x^3)
__device__ __forceinline__ float gelu_fast(float x) {
    float z = x * (1.5957691216f + 0.0713548163f * x * x);
    return x / (1.f + __expf(-z));
}

#define GCAST(p) ((const __attribute__((address_space(1))) void*)(p))
#define LCAST(p) ((__attribute__((address_space(3))) void*)(p))

enum { ME_F32 = 0, ME_BF16, ME_DCBIAS_BF16, ME_BIASCOL_BF16,
       ME_BIASCOL_ACCB16, ME_GELU_BF16, ME_RESB_BF16, ME_TREND };

// ----- 128x128 GEMM, 8 waves of 32x64 (R12 config), 3-buf counted vmcnt ----
template<int EPI>
__global__ __launch_bounds__(512)
void mgemm_k(const ushort_t* __restrict__ A, const ushort_t* __restrict__ B,
             const float* __restrict__ bias, const ushort_t* __restrict__ Resb,
             void* __restrict__ Cv,
             int M, int N, int K, int ldc, int ldres,
             long sA, long sB, long sC, long sRes)
{
    const int gx = gridDim.x, gy = gridDim.y;
    const int nwg = gx * gy * gridDim.z;
    const int lin = (blockIdx.z * gy + blockIdx.y) * gx + blockIdx.x;
    const int cpx = nwg >> 3;
    const int swz = (nwg & 7) ? lin : ((lin & 7) * cpx + (lin >> 3));
    const int bx = swz % gx;
    const int t2 = swz / gx;
    const int by = t2 % gy;
    const int bz = t2 / gy;

    A += bz * sA;
    B += bz * sB;
    const int m0 = by * 128, n0 = bx * 128;

    __shared__ __align__(16) ushort_t As[3][4096];
    __shared__ __align__(16) ushort_t Bs[3][4096];

    const int tid = threadIdx.x;
    const int wave = tid >> 6, lane = tid & 63;
    const int wr = wave >> 1, wc = wave & 1;

    f32x4_t acc[2][4] = {};

    const int srow = tid >> 2;
    // pre-swizzled k-chunk: chunk' = chunk ^ (row & 3)  (LDS dest stays linear)
    const int skof = (((tid & 3) ^ ((tid >> 2) & 3)) << 3);

    const ushort_t* ga = A + (long)(m0 + srow) * K + skof;
    const ushort_t* gb = B + (long)(n0 + srow) * K + skof;
    const int nt = K >> 5;

#define STG(s, bidx) { const long ko = (long)(s) << 5; \
    __builtin_amdgcn_global_load_lds(GCAST(ga + ko), LCAST(As[bidx] + wave * 512), 16, 0, 0); \
    __builtin_amdgcn_global_load_lds(GCAST(gb + ko), LCAST(Bs[bidx] + wave * 512), 16, 0, 0); }

    STG(0, 0)
    STG(1, 1)

    const int q = lane >> 4;             // k-chunk 0..3
    int cbuf = 0;

    for (int t = 0; t < nt; ++t) {
        if (t + 1 < nt) { asm volatile("s_waitcnt vmcnt(2)" ::: "memory"); }
        else            { asm volatile("s_waitcnt vmcnt(0)" ::: "memory"); }
        __builtin_amdgcn_s_barrier();
        asm volatile("" ::: "memory");
        __builtin_amdgcn_sched_barrier(0);
        if (t + 2 < nt) { int nb = cbuf + 2; if (nb >= 3) nb -= 3; STG(t + 2, nb) }

        bf16x8_t a[2], b[4];
        #pragma unroll
        for (int i = 0; i < 2; ++i) {
            int ra = wr * 32 + i * 16 + (lane & 15);
            a[i] = *(const bf16x8_t*)&As[cbuf][ra * 32 + ((q ^ (ra & 3)) << 3)];
        }
        #pragma unroll
        for (int j = 0; j < 4; ++j) {
            int rb = wc * 64 + j * 16 + (lane & 15);
            b[j] = *(const bf16x8_t*)&Bs[cbuf][rb * 32 + ((q ^ (rb & 3)) << 3)];
        }
        #pragma unroll
        for (int i = 0; i < 2; ++i)
            #pragma unroll
            for (int j = 0; j < 4; ++j)
                acc[i][j] = __builtin_amdgcn_mfma_f32_16x16x32_bf16(a[i], b[j], acc[i][j], 0, 0, 0);
        ++cbuf; if (cbuf >= 3) cbuf = 0;
    }
#undef STG

    float*    Cf  = (float*)Cv + bz * sC;
    ushort_t* Cb  = (ushort_t*)Cv + bz * sC;
    const ushort_t* R = Resb ? Resb + bz * sRes : nullptr;

    #pragma unroll
    for (int i = 0; i < 2; ++i) {
        #pragma unroll
        for (int j = 0; j < 4; ++j) {
            #pragma unroll
            for (int r = 0; r < 4; ++r) {
                int gm = m0 + wr * 32 + i * 16 + (lane >> 4) * 4 + r;
                int gn = n0 + wc * 64 + j * 16 + (lane & 15);
                float v = acc[i][j][r];
                long idx = (long)gm * ldc + gn;
                if (EPI == ME_F32)               Cf[idx] = v;
                else if (EPI == ME_BF16)         Cb[idx] = f2b(v);
                else if (EPI == ME_BIASCOL_BF16) Cb[idx] = f2b(v + bias[gn]);
                else if (EPI == ME_BIASCOL_ACCB16) Cb[idx] = f2b(b2f(Cb[idx]) + v + bias[gn]);
                else if (EPI == ME_GELU_BF16)    Cb[idx] = f2b(gelu_fast(v));
                else if (EPI == ME_RESB_BF16)    Cb[idx] = f2b(v + b2f(R[(long)gm * ldres + gn]));
            }
        }
    }
}

// ---------------- 64x64 GEMM, 4 waves, 3-buf, swizzled ---------------------
template<int EPI>
__global__ __launch_bounds__(256)
void sgemm_k(const ushort_t* __restrict__ A, const ushort_t* __restrict__ B,
             const float* __restrict__ bias, void* __restrict__ Cv,
             int M, int N, int K, int ldc,
             long sA, long sB, long sC)
{
    const int gx = gridDim.x, gy = gridDim.y;
    const int nwg = gx * gy * gridDim.z;
    const int lin = (blockIdx.z * gy + blockIdx.y) * gx + blockIdx.x;
    const int cpx = nwg >> 3;
    const int swz = (nwg & 7) ? lin : ((lin & 7) * cpx + (lin >> 3));
    const int bx = swz % gx;
    const int t2 = swz / gx;
    const int by = t2 % gy;
    const int bz = t2 / gy;

    A += bz * sA;
    B += bz * sB;
    const int m0 = by * 64, n0 = bx * 64;

    __shared__ __align__(16) ushort_t As[3][2048];
    __shared__ __align__(16) ushort_t Bs[3][2048];

    const int tid = threadIdx.x;
    const int wave = tid >> 6, lane = tid & 63;
    const int wr = wave >> 1, wc = wave & 1;

    f32x4_t acc[2][2] = {};

    const int skof = (((tid & 3) ^ ((tid >> 2) & 3)) << 3);
    const int srow = tid >> 2;

    const ushort_t* ga = A + (long)(m0 + srow) * K + skof;
    const ushort_t* gb = B + (long)(n0 + srow) * K + skof;
    const int nt = K >> 5;

#define STG(s, bidx) { const long ko = (long)(s) << 5; \
    __builtin_amdgcn_global_load_lds(GCAST(ga + ko), LCAST(As[bidx] + wave * 512), 16, 0, 0); \
    __builtin_amdgcn_global_load_lds(GCAST(gb + ko), LCAST(Bs[bidx] + wave * 512), 16, 0, 0); }

    STG(0, 0)
    STG(1, 1)

    const int q = lane >> 4;
    int cbuf = 0;

    for (int t = 0; t < nt; ++t) {
        if (t + 1 < nt) { asm volatile("s_waitcnt vmcnt(2)" ::: "memory"); }
        else            { asm volatile("s_waitcnt vmcnt(0)" ::: "memory"); }
        __builtin_amdgcn_s_barrier();
        asm volatile("" ::: "memory");
        __builtin_amdgcn_sched_barrier(0);
        if (t + 2 < nt) { int nb = cbuf + 2; if (nb >= 3) nb -= 3; STG(t + 2, nb) }

        bf16x8_t a[2], b[2];
        #pragma unroll
        for (int i = 0; i < 2; ++i) {
            int ra = wr * 32 + i * 16 + (lane & 15);
            a[i] = *(const bf16x8_t*)&As[cbuf][ra * 32 + ((q ^ (ra & 3)) << 3)];
        }
        #pragma unroll
        for (int j = 0; j < 2; ++j) {
            int rb = wc * 32 + j * 16 + (lane & 15);
            b[j] = *(const bf16x8_t*)&Bs[cbuf][rb * 32 + ((q ^ (rb & 3)) << 3)];
        }
        #pragma unroll
        for (int i = 0; i < 2; ++i)
            #pragma unroll
            for (int j = 0; j < 2; ++j)
                acc[i][j] = __builtin_amdgcn_mfma_f32_16x16x32_bf16(a[i], b[j], acc[i][j], 0, 0, 0);
        ++cbuf; if (cbuf >= 3) cbuf = 0;
    }
#undef STG

    float*    Cf = (float*)Cv + bz * sC;
    ushort_t* Cb = (ushort_t*)Cv + bz * sC;

    #pragma unroll
    for (int i = 0; i < 2; ++i) {
        #pragma unroll
        for (int j = 0; j < 2; ++j) {
            #pragma unroll
            for (int r = 0; r < 4; ++r) {
                int gm = m0 + wr * 32 + i * 16 + (lane >> 4) * 4 + r;
                int gn = n0 + wc * 32 + j * 16 + (lane & 15);
                float v = acc[i][j][r];
                long idx = (long)gm * ldc + gn;
                if (EPI == ME_F32)               Cf[idx] = v;
                else if (EPI == ME_BF16)         Cb[idx] = f2b(v);
                else if (EPI == ME_DCBIAS_BF16)  Cb[idx] = f2b(v + (gn == 0 ? 512.f * bias[gm] : 0.f));
                else if (EPI == ME_TREND) { if (gm < 96) Cf[idx] = v + bias[gm]; }
            }
        }
    }
}

// -------- batched complex mode-mix MFMA (per h,m), swizzled LDS ------------
__global__ __launch_bounds__(256)
void fmix_k(const ushort_t* __restrict__ A2, const ushort_t* __restrict__ B2,
            ushort_t* __restrict__ OS)
{
    const int hm = blockIdx.x;
    const int h = hm >> 6, m = hm & 63;
    __shared__ __align__(16) ushort_t As[32 * 128];
    __shared__ __align__(16) ushort_t Bs[128 * 128];

    const int tid = threadIdx.x;
    const int w = tid >> 6, lane = tid & 63;

    const ushort_t* Ag = A2 + (long)hm * 4096;
    const ushort_t* Bg = B2 + (long)hm * 16384;
    #pragma unroll
    for (int r = 0; r < 2; ++r) {
        int rowA = w * 8 + r * 4 + (lane >> 4);
        const ushort_t* src = Ag + rowA * 128 + (((lane & 15) ^ (rowA & 15)) << 3);
        __builtin_amdgcn_global_load_lds(GCAST(src), LCAST(As + w * 1024 + r * 512), 16, 0, 0);
    }
    #pragma unroll
    for (int r = 0; r < 8; ++r) {
        int rowB = w * 32 + r * 4 + (lane >> 4);
        const ushort_t* src = Bg + rowB * 128 + (((lane & 15) ^ (rowB & 15)) << 3);
        __builtin_amdgcn_global_load_lds(GCAST(src), LCAST(Bs + w * 4096 + r * 512), 16, 0, 0);
    }
    __syncthreads();

    f32x4_t acc[2][2] = {};
    #pragma unroll
    for (int kk = 0; kk < 4; ++kk) {
        const int cq = kk * 4 + (lane >> 4);
        bf16x8_t a[2], b[2];
        #pragma unroll
        for (int i = 0; i < 2; ++i) {
            int ra = i * 16 + (lane & 15);
            a[i] = *(const bf16x8_t*)&As[ra * 128 + ((cq ^ (ra & 15)) << 3)];
        }
        #pragma unroll
        for (int j = 0; j < 2; ++j) {
            int rb = w * 32 + j * 16 + (lane & 15);
            b[j] = *(const bf16x8_t*)&Bs[rb * 128 + ((cq ^ (rb & 15)) << 3)];
        }
        #pragma unroll
        for (int i = 0; i < 2; ++i)
            #pragma unroll
            for (int j = 0; j < 2; ++j)
                acc[i][j] = __builtin_amdgcn_mfma_f32_16x16x32_bf16(a[i], b[j], acc[i][j], 0, 0, 0);
    }

    #pragma unroll
    for (int i = 0; i < 2; ++i) {
        #pragma unroll
        for (int j = 0; j < 2; ++j) {
            #pragma unroll
            for (int r = 0; r < 4; ++r) {
                int b = i * 16 + (lane >> 4) * 4 + r;
                int n2 = w * 32 + j * 16 + (lane & 15);
                int o = n2 & 63, ri = n2 >> 6;
                OS[((long)b * 512 + h * 64 + o) * 128 + ri * 64 + m] = f2b(acc[i][j][r]);
            }
        }
    }
}

// B2 prep: block per (h,o). Fr/Fi [h][i][o][m] f32 -> B2[h][m][n2][k2] bf16
__global__ __launch_bounds__(256)
void bprep_k(const float* __restrict__ FR, const float* __restrict__ FI,
             ushort_t* __restrict__ B2)
{
    const int bx = blockIdx.x;
    const int h = bx >> 6, o = bx & 63;
    __shared__ float fr_s[64][65];
    __shared__ float fi_s[64][65];
    for (int e = threadIdx.x; e < 4096; e += 256) {
        int i = e >> 6, m = e & 63;
        long src = ((long)(h * 64 + i) * 64 + o) * 64 + m;
        fr_s[i][m] = FR[src];
        fi_s[i][m] = FI[src];
    }
    __syncthreads();
    const int m = threadIdx.x & 63;
    const int kq = threadIdx.x >> 6;
    ushort_t* b0 = B2 + ((long)(h * 64 + m) * 128 + o) * 128;
    ushort_t* b1 = B2 + ((long)(h * 64 + m) * 128 + o + 64) * 128;
    for (int kk = 0; kk < 32; ++kk) {
        int k2 = kq * 32 + kk;
        int ik = k2 & 63, hi = k2 >> 6;
        float fr = fr_s[ik][m], fi = fi_s[ik][m];
        b0[k2] = f2b(hi ? -fi : fr);
        b1[k2] = f2b(hi ?  fr : fi);
    }
}

// A2 prep: block per (b,h). XFTb [b][c=h*64+i][mp] bf16 -> A2[h][m][b][k2] bf16
__global__ __launch_bounds__(256)
void aprep_k(const ushort_t* __restrict__ XFTb, ushort_t* __restrict__ A2)
{
    const int bx = blockIdx.x;
    const int b = bx >> 3, h = bx & 7;
    __shared__ ushort_t xs[64][130];
    for (int e = threadIdx.x; e < 8192; e += 256) {
        int i = e >> 7, mp = e & 127;
        xs[i][mp] = XFTb[((long)b * 512 + h * 64 + i) * 128 + mp];
    }
    __syncthreads();
    const int m = threadIdx.x & 63;
    const int kq = threadIdx.x >> 6;
    ushort_t* dst = A2 + ((long)(h * 64 + m) * 32 + b) * 128;
    for (int kk = 0; kk < 32; ++kk) {
        int k2 = kq * 32 + kk;
        int i = k2 & 63, ri = k2 >> 6;
        dst[k2] = xs[i][ri * 64 + m];
    }
}

// ------- start decomp (k=25), f32 in -> TRANSPOSED bf16 seasonal/trend -----
__global__ __launch_bounds__(256)
void decomp2t_k(const float* __restrict__ X, ushort_t* __restrict__ SbT,
                ushort_t* __restrict__ TrbT)
{
    const int id = blockIdx.x;
    const int ch = id & 1, rc = (id >> 1) & 31, b = id >> 6;
    const int c = ch * 256 + threadIdx.x;
    const int r0 = rc * 16;
    const long base = ((long)b << 18) + c;
    float s = 0.f;
    #pragma unroll
    for (int j = -12; j <= 12; ++j) {
        int rr = r0 + j; rr = rr < 0 ? 0 : (rr > 511 ? 511 : rr);
        s += X[base + ((long)rr << 9)];
    }
    u16x8_t sv0, sv1, tv0, tv1;
    for (int rr = 0; rr < 16; ++rr) {
        int r = r0 + rr;
        float mean = s * (1.f / 25.f);
        float x = X[base + ((long)r << 9)];
        if (rr < 8) { sv0[rr] = f2b(x - mean); tv0[rr] = f2b(mean); }
        else        { sv1[rr - 8] = f2b(x - mean); tv1[rr - 8] = f2b(mean); }
        int rp = r + 13; rp = rp > 511 ? 511 : rp;
        int rm = r - 12; rm = rm < 0 ? 0 : rm;
        s += X[base + ((long)rp << 9)] - X[base + ((long)rm << 9)];
    }
    long obase = (long)b * 262144 + (long)c * 512 + r0;
    *(u16x8_t*)&SbT[obase] = sv0;  *(u16x8_t*)&SbT[obase + 8] = sv1;
    *(u16x8_t*)&TrbT[obase] = tv0; *(u16x8_t*)&TrbT[obase + 8] = tv1;
}

// ------- sliding-window series_decomp (k=25), bf16 in/out, vectorized ------
// optional ST: also emit transposed output ST[b][d][n] (8x8 register tiles)
__global__ __launch_bounds__(256)
void decomp2v_k(const ushort_t* __restrict__ Xb, ushort_t* __restrict__ Sb,
                ushort_t* __restrict__ ST)
{
    const int id = blockIdx.x;
    const int b = id >> 4, rc = id & 15;
    const int c0 = (threadIdx.x & 63) * 8;
    const int rsub = threadIdx.x >> 6;
    const int r0 = rc * 32 + rsub * 8;
    const ushort_t* base = Xb + ((long)b << 18) + c0;
    ushort_t* obase = Sb + ((long)b << 18) + c0;

    float s[8] = {};
    #pragma unroll
    for (int j = -12; j <= 12; ++j) {
        int rr = r0 + j; rr = rr < 0 ? 0 : (rr > 511 ? 511 : rr);
        u16x8_t v = *(const u16x8_t*)(base + ((long)rr << 9));
        #pragma unroll
        for (int k = 0; k < 8; ++k) s[k] += b2f(v[k]);
    }
    u16x8_t tile[8];
    #pragma unroll
    for (int rr = 0; rr < 8; ++rr) {
        int r = r0 + rr;
        u16x8_t xv = *(const u16x8_t*)(base + ((long)r << 9));
        u16x8_t ov;
        #pragma unroll
        for (int k = 0; k < 8; ++k) ov[k] = f2b(b2f(xv[k]) - s[k] * (1.f / 25.f));
        *(u16x8_t*)(obase + ((long)r << 9)) = ov;
        tile[rr] = ov;
        int rp = r + 13; rp = rp > 511 ? 511 : rp;
        int rm = r - 12; rm = rm < 0 ? 0 : rm;
        u16x8_t vp = *(const u16x8_t*)(base + ((long)rp << 9));
        u16x8_t vm = *(const u16x8_t*)(base + ((long)rm << 9));
        #pragma unroll
        for (int k = 0; k < 8; ++k) s[k] += b2f(vp[k]) - b2f(vm[k]);
    }
    if (ST) {
        ushort_t* tb = ST + ((long)b << 18);
        #pragma unroll
        for (int k = 0; k < 8; ++k) {
            u16x8_t col;
            #pragma unroll
            for (int rr = 0; rr < 8; ++rr) col[rr] = tile[rr][k];
            *(u16x8_t*)(tb + (long)(c0 + k) * 512 + r0) = col;
        }
    }
}

// ----------------------- bf16 DFT tables -----------------------------------
__global__ __launch_bounds__(256)
void init_tables_k(ushort_t* __restrict__ TFb, ushort_t* __restrict__ TI2b)
{
    int t = blockIdx.x * 256 + threadIdx.x;   // 0..131071
    const float w = 6.283185307179586f / 512.f;
    if (t < 65536) {
        int mp = t >> 9, n = t & 511;
        int m = mp & 63;
        float ang = ((m * n) & 511) * w;
        TFb[t] = f2b((mp < 64) ? cosf(ang) : -sinf(ang));
    } else {
        int u = t - 65536;
        int mp = u >> 9, n = u & 511;
        int m = mp & 63;
        float ang = ((m * n) & 511) * w;
        float v;
        if (mp < 64) v = (m == 0) ? (1.f / 512.f) : (2.f / 512.f) * cosf(ang);
        else         v = (m == 0) ? 0.f : -(2.f / 512.f) * sinf(ang);
        TI2b[u] = f2b(v);
    }
}

// ----------------------- fp32 -> bf16 convert (weights) --------------------
__global__ __launch_bounds__(256)
void f2b_k(const float* __restrict__ X, ushort_t* __restrict__ Y, long n)
{
    long i = ((long)blockIdx.x * 256 + threadIdx.x) * 8;
    if (i >= n) return;
    const float4* xp = (const float4*)(X + i);
    float4 v0 = xp[0], v1 = xp[1];
    u16x8_t o;
    o[0] = f2b(v0.x); o[1] = f2b(v0.y); o[2] = f2b(v0.z); o[3] = f2b(v0.w);
    o[4] = f2b(v1.x); o[5] = f2b(v1.y); o[6] = f2b(v1.z); o[7] = f2b(v1.w);
    *(u16x8_t*)(Y + i) = o;
}

// ----------------- fp32 [R,C] -> bf16 transposed [C,R] ---------------------
__global__ __launch_bounds__(256)
void trans_b_k(const float* __restrict__ X, ushort_t* __restrict__ Y,
               int R, int C, long sX, long sY)
{
    __shared__ float t[32][33];
    X += (long)blockIdx.z * sX;
    Y += (long)blockIdx.z * sY;
    int r0 = blockIdx.y * 32, c0 = blockIdx.x * 32;
    int tx = threadIdx.x & 31, ty = threadIdx.x >> 5;
    #pragma unroll
    for (int i = ty; i < 32; i += 8)
        t[i][tx] = X[(long)(r0 + i) * C + c0 + tx];
    __syncthreads();
    #pragma unroll
    for (int i = ty; i < 32; i += 8)
        Y[(long)(c0 + i) * R + r0 + tx] = f2b(t[tx][i]);
}

// ----------------- bf16 [R,C] -> bf16 transposed [C,R] ---------------------
__global__ __launch_bounds__(256)
void trans_bb_k(const ushort_t* __restrict__ X, ushort_t* __restrict__ Y,
                int R, int C, long sX, long sY)
{
    __shared__ ushort_t t[32][34];
    X += (long)blockIdx.z * sX;
    Y += (long)blockIdx.z * sY;
    int r0 = blockIdx.y * 32, c0 = blockIdx.x * 32;
    int tx = threadIdx.x & 31, ty = threadIdx.x >> 5;
    #pragma unroll
    for (int i = ty; i < 32; i += 8)
        t[i][tx] = X[(long)(r0 + i) * C + c0 + tx];
    __syncthreads();
    #pragma unroll
    for (int i = ty; i < 32; i += 8)
        Y[(long)(c0 + i) * R + r0 + tx] = t[tx][i];
}

// --------------------- layernorm (bf16 in/out, f32 math) -------------------
__global__ __launch_bounds__(256)
void ln_rows_bb_k(const ushort_t* __restrict__ Xb, const float* __restrict__ g,
                  const float* __restrict__ bta, ushort_t* __restrict__ Yb)
{
    int wave = threadIdx.x >> 6, lane = threadIdx.x & 63;
    long row = (long)blockIdx.x * 4 + wave;
    const ushort_t* x = Xb + row * 512 + lane * 8;
    u16x8_t v = *(const u16x8_t*)x;
    float f[8];
    float s = 0.f, ss = 0.f;
    #pragma unroll
    for (int j = 0; j < 8; ++j) { f[j] = b2f(v[j]); s += f[j]; ss += f[j] * f[j]; }
    #pragma unroll
    for (int o = 32; o; o >>= 1) { s += __shfl_xor(s, o); ss += __shfl_xor(ss, o); }
    float mu = s * (1.f / 512.f);
    float var = ss * (1.f / 512.f) - mu * mu;
    float inv = rsqrtf(var + 1e-5f);
    u16x8_t ov;
    #pragma unroll
    for (int j = 0; j < 8; ++j)
        ov[j] = f2b((f[j] - mu) * inv * g[lane * 8 + j] + bta[lane * 8 + j]);
    *(u16x8_t*)(Yb + row * 512 + lane * 8) = ov;
}

// subtract per-(b,d) seq-mean, bf16 in/out (4 waves split the t-loop)
__global__ __launch_bounds__(256)
void colmean_bb_k(const ushort_t* __restrict__ Y, ushort_t* __restrict__ O)
{
    __shared__ float ps[4][64];
    int b = blockIdx.x, dg = blockIdx.y;
    int wave = threadIdx.x >> 6, lane = threadIdx.x & 63;
    int d = dg * 64 + lane;
    long base = (long)b * 262144 + d;
    float s = 0.f;
    for (int t = wave * 128; t < wave * 128 + 128; ++t)
        s += b2f(Y[base + ((long)t << 9)]);
    ps[wave][lane] = s;
    __syncthreads();
    float mean = (ps[0][lane] + ps[1][lane] + ps[2][lane] + ps[3][lane]) * (1.f / 512.f);
    for (int t = wave * 128; t < wave * 128 + 128; ++t)
        O[base + ((long)t << 9)] = f2b(b2f(Y[base + ((long)t << 9)]) - mean);
}

// head transpose-add: out[b,p,t] += Thead[(b*512+t)*128+p] + b_head[p]
__global__ __launch_bounds__(256)
void headadd_k(const float* __restrict__ Th, const float* __restrict__ bh,
               float* __restrict__ out)
{
    const int id = blockIdx.x;          // b*16 + tc
    const int b = id >> 4, t0 = (id & 15) * 32;
    __shared__ float tile[32][100];
    for (int e = threadIdx.x; e < 32 * 96; e += 256) {
        int tl = e / 96, p = e - tl * 96;
        tile[tl][p] = Th[((long)(b * 512 + t0 + tl)) * 128 + p];
    }
    __syncthreads();
    for (int e = threadIdx.x; e < 96 * 32; e += 256) {
        int p = e >> 5, tl = e & 31;
        out[(long)b * 49152 + p * 512 + t0 + tl] += tile[tl][p] + bh[p];
    }
}

// ===========================================================================
extern "C" void kernel_launch(void* const* d_in, const int* in_sizes, int n_in,
                              void* d_out, int out_size, void* d_ws, size_t ws_size,
                              hipStream_t stream)
{
    const float* x_enc   = (const float*)d_in[0];
    const float* W_trend = (const float*)d_in[4];
    const float* b_trend = (const float*)d_in[5];
    const float* W_emb   = (const float*)d_in[6];
    const float* b_emb   = (const float*)d_in[7];
    const float* Wq      = (const float*)d_in[8];
    const float* bq      = (const float*)d_in[9];
    const float* fw_r    = (const float*)d_in[14];
    const float* fw_i    = (const float*)d_in[15];
    const float* Wo      = (const float*)d_in[16];
    const float* bo      = (const float*)d_in[17];
    const float* W1      = (const float*)d_in[18];
    const float* W2      = (const float*)d_in[19];
    const float* ln_g    = (const float*)d_in[20];
    const float* ln_b    = (const float*)d_in[21];
    const float* W_head  = (const float*)d_in[22];
    const float* b_head  = (const float*)d_in[23];
    float* out = (float*)d_out;
    float* ws  = (float*)d_ws;

    const long F = 8388608;
    float* G    = ws;
    ushort_t* xw  = (ushort_t*)(ws + 3 * F);           // encoder state bf16
    ushort_t* xs  = (ushort_t*)(ws + 4 * F);           // seasonal / FFN residual
    ushort_t* T1b = xs + 8388608;                      // FFN out / LN out
    ushort_t* qT  = (ushort_t*)(ws + 5 * F);           // seasT at start

    ushort_t* trendT = (ushort_t*)G;
    ushort_t* XFTb  = (ushort_t*)G;                    // [0,4MB)
    ushort_t* Yb    = (ushort_t*)(G + 1048576);        // [4,8MB)
    ushort_t* A2    = (ushort_t*)(G + 2097152);        // [8,12MB)
    ushort_t* OSELb = (ushort_t*)(G + 3145728);        // [12,16MB)
    ushort_t* xbT   = (ushort_t*)(G + 4194304);        // [16,32MB)
    ushort_t* B2    = (ushort_t*)(G + 8388608);        // [32,48MB)
    float*    Thead = G;
    ushort_t* gb    = (ushort_t*)G;                    // FFN-phase 64MB

    ushort_t* WembT  = (ushort_t*)(ws + 6 * F);        // 262144
    ushort_t* WTq2   = WembT + 262144;                 // 2 x 262144
    ushort_t* WTo2   = WTq2 + 524288;                  // 2 x 262144
    ushort_t* W1b2   = WTo2 + 524288;                  // 2 x 1048576
    ushort_t* W2b2   = W1b2 + 2097152;                 // 2 x 1048576
    ushort_t* TFb    = W2b2 + 2097152;                 // 65536
    ushort_t* TI2b   = TFb + 65536;                    // 65536
    ushort_t* WtT    = TI2b + 65536;
    ushort_t* WheadT = WtT + 65536;
    ushort_t* TIWob2 = WheadT + 65536;                 // 2 x 65536

    dim3 blk(256), blk5(512);

    init_tables_k<<<dim3(512), blk, 0, stream>>>(TFb, TI2b);

    // decomp(x_enc) -> TRANSPOSED seasonal (qT) + trend (G)
    decomp2t_k<<<dim3(2048), blk, 0, stream>>>(x_enc, qT, trendT);

    // hoisted weight prep (both layers batched)
    trans_b_k<<<dim3(3, 16, 1), blk, 0, stream>>>(W_trend, WtT, 512, 96, 0L, 0L);
    trans_b_k<<<dim3(3, 16, 1), blk, 0, stream>>>(W_head, WheadT, 512, 96, 0L, 0L);
    trans_b_k<<<dim3(16, 16, 1), blk, 0, stream>>>(W_emb, WembT, 512, 512, 0L, 0L);
    trans_b_k<<<dim3(16, 16, 2), blk, 0, stream>>>(Wq, WTq2, 512, 512, 262144L, 262144L);
    trans_b_k<<<dim3(16, 16, 2), blk, 0, stream>>>(Wo, WTo2, 512, 512, 262144L, 262144L);
    f2b_k<<<dim3(1024), blk, 0, stream>>>(W1, W1b2, 2097152L);
    f2b_k<<<dim3(1024), blk, 0, stream>>>(W2, W2b2, 2097152L);
    sgemm_k<ME_BF16><<<dim3(2, 8, 2), blk, 0, stream>>>(
        WTo2, TI2b, nullptr, TIWob2,
        512, 128, 512, 128, 262144L, 0L, 65536L);

    // trend head GEMM -> out
    sgemm_k<ME_TREND><<<dim3(8, 2, 32), blk, 0, stream>>>(
        WtT, trendT, b_trend, out,
        128, 512, 512, 512, 0L, 262144L, 49152L);

    // embedding -> xw bf16
    mgemm_k<ME_BIASCOL_BF16><<<dim3(4, 4, 32), blk5, 0, stream>>>(
        qT, WembT, b_emb, nullptr, xw,
        512, 512, 512, 512, 0, 262144L, 0L, 262144L, 0L);

    for (int l = 0; l < 2; ++l) {
        const float* bq_l = bq + (long)l * 512;
        const float* bo_l = bo + (long)l * 512;
        const float* fr_l = fw_r + (long)l * 2097152;
        const float* fi_l = fw_i + (long)l * 2097152;
        const ushort_t* WTq_l   = WTq2 + (long)l * 262144;
        const ushort_t* W1b_l   = W1b2 + (long)l * 1048576;
        const ushort_t* W2b_l   = W2b2 + (long)l * 1048576;
        const ushort_t* TIWob_l = TIWob2 + (long)l * 65536;

        bprep_k<<<dim3(512), blk, 0, stream>>>(fr_l, fi_l, B2);

        // xbT[b,d,n] = xw[b,n,d]^T  (layer 1: already emitted by decomp2v)
        if (l == 0)
            trans_bb_k<<<dim3(16, 16, 32), blk, 0, stream>>>(xw, xbT, 512, 512, 262144L, 262144L);

        // G1: Yb[b,mp,d] = sum_n TFb[mp,n] * xbT[b,d,n]
        sgemm_k<ME_BF16><<<dim3(8, 2, 32), blk, 0, stream>>>(
            TFb, xbT, nullptr, Yb,
            128, 512, 512, 512, 0L, 262144L, 65536L);

        // G2: XFTb[b,c,mp] = sum_d WTq[c,d] * Yb[b,mp,d]  (+512*bq[c] at mp=0)
        sgemm_k<ME_DCBIAS_BF16><<<dim3(2, 8, 32), blk, 0, stream>>>(
            WTq_l, Yb, bq_l, XFTb,
            512, 128, 512, 128, 0L, 65536L, 65536L);

        aprep_k<<<dim3(256), blk, 0, stream>>>(XFTb, A2);
        fmix_k<<<dim3(512), blk, 0, stream>>>(A2, B2, OSELb);

        // xw += OSEL . TIWo^T + bo   (bf16 RMW)
        mgemm_k<ME_BIASCOL_ACCB16><<<dim3(4, 128, 1), blk5, 0, stream>>>(
            OSELb, TIWob_l, bo_l, nullptr, xw,
            16384, 512, 128, 512, 0, 0L, 0L, 0L, 0L);

        // decomp (bf16, vectorized) -> xs (FFN input + FFN2 residual)
        decomp2v_k<<<dim3(512), blk, 0, stream>>>(xw, xs, nullptr);

        // FFN, full M=16384
        mgemm_k<ME_GELU_BF16><<<dim3(16, 128, 1), blk5, 0, stream>>>(
            xs, W1b_l, nullptr, nullptr, gb,
            16384, 2048, 512, 2048, 0, 0L, 0L, 0L, 0L);
        mgemm_k<ME_RESB_BF16><<<dim3(4, 128, 1), blk5, 0, stream>>>(
            gb, W2b_l, nullptr, xs, T1b,
            16384, 512, 2048, 512, 512, 0L, 0L, 0L, 0L);

        // decomp (bf16) -> xw; layer 0 also emits xbT for layer 1's G1
        decomp2v_k<<<dim3(512), blk, 0, stream>>>(T1b, xw, (l == 0) ? xbT : nullptr);
    }

    // my_layernorm (bf16): rows -> T1b, colmean-subtract -> xs
    ln_rows_bb_k<<<dim3(4096), blk, 0, stream>>>(xw, ln_g, ln_b, T1b);
    colmean_bb_k<<<dim3(32, 8), blk, 0, stream>>>(T1b, xs);

    // head
    sgemm_k<ME_F32><<<dim3(2, 256, 1), blk, 0, stream>>>(
        xs, WheadT, nullptr, Thead,
        16384, 128, 512, 128, 0L, 0L, 0L);

    headadd_k<<<dim3(512), blk, 0, stream>>>(Thead, b_head, out);
}

// Round 15
// 545.801 us; speedup vs baseline: 1.0227x; 1.0227x over previous
//
#include <hip/hip_runtime.h>
#include <math.h>

// ---------------------------------------------------------------------------
// Model_24180665876772  Round 15: exact revert to R12 (best verified: 546us).
// R14's transposed-store decomp fusion regressed (+12us: scattered 16B
// stores 8KB apart vs coalesced LDS-staged transpose). R12 config restored:
// 8-wave 32x64 mgemm + 3-buf counted vmcnt, sgemm 64x64, swizzled fmix,
// start-decomp transposed fusion, per-layer trans_bb, bf16 state end-to-end.
// ---------------------------------------------------------------------------

typedef unsigned short ushort_t;
typedef unsigned int uint_t;
using bf16x8_t = __attribute__((ext_vector_type(8))) short;
using f32x4_t  = __attribute__((ext_vector_type(4))) float;
using u16x8_t  = __attribute__((ext_vector_type(8))) unsigned short;

__device__ __forceinline__ unsigned short f2b(float x) {
    union { float f; uint_t u; } c; c.f = x;
    uint_t r = c.u + 0x7fffu + ((c.u >> 16) & 1u);   // RNE
    return (unsigned short)(r >> 16);
}
__device__ __forceinline__ float b2f(unsigned short h) {
    union { uint_t u; float f; } c; c.u = ((uint_t)h) << 16; return c.f;
}
// tanh-form GELU via sigmoid: gelu(x) ~= x * sigmoid(1.59577x + 0.0713548x^3)
__device__ __forceinline__ float gelu_fast(float x) {
    float z = x * (1.5957691216f + 0.0713548163f * x * x);
    return x / (1.f + __expf(-z));
}

#define GCAST(p) ((const __attribute__((address_space(1))) void*)(p))
#define LCAST(p) ((__attribute__((address_space(3))) void*)(p))

enum { ME_F32 = 0, ME_BF16, ME_DCBIAS_BF16, ME_BIASCOL_BF16,
       ME_BIASCOL_ACCB16, ME_GELU_BF16, ME_RESB_BF16, ME_TREND };

// ---------------- 128x128 GEMM, 8 waves, 3-buf, counted vmcnt --------------
template<int EPI>
__global__ __launch_bounds__(512)
void mgemm_k(const ushort_t* __restrict__ A, const ushort_t* __restrict__ B,
             const float* __restrict__ bias, const ushort_t* __restrict__ Resb,
             void* __restrict__ Cv,
             int M, int N, int K, int ldc, int ldres,
             long sA, long sB, long sC, long sRes)
{
    const int gx = gridDim.x, gy = gridDim.y;
    const int nwg = gx * gy * gridDim.z;
    const int lin = (blockIdx.z * gy + blockIdx.y) * gx + blockIdx.x;
    const int cpx = nwg >> 3;
    const int swz = (nwg & 7) ? lin : ((lin & 7) * cpx + (lin >> 3));
    const int bx = swz % gx;
    const int t2 = swz / gx;
    const int by = t2 % gy;
    const int bz = t2 / gy;

    A += bz * sA;
    B += bz * sB;
    const int m0 = by * 128, n0 = bx * 128;

    __shared__ __align__(16) ushort_t As[3][4096];
    __shared__ __align__(16) ushort_t Bs[3][4096];

    const int tid = threadIdx.x;
    const int wave = tid >> 6, lane = tid & 63;
    const int wr = wave >> 1, wc = wave & 1;

    f32x4_t acc[2][4] = {};

    const int srow = tid >> 2;
    // pre-swizzled k-chunk: chunk' = chunk ^ (row & 3)  (LDS dest stays linear)
    const int skof = (((tid & 3) ^ ((tid >> 2) & 3)) << 3);

    const ushort_t* ga = A + (long)(m0 + srow) * K + skof;
    const ushort_t* gb = B + (long)(n0 + srow) * K + skof;
    const int nt = K >> 5;

#define STG(s, bidx) { const long ko = (long)(s) << 5; \
    __builtin_amdgcn_global_load_lds(GCAST(ga + ko), LCAST(As[bidx] + wave * 512), 16, 0, 0); \
    __builtin_amdgcn_global_load_lds(GCAST(gb + ko), LCAST(Bs[bidx] + wave * 512), 16, 0, 0); }

    STG(0, 0)
    STG(1, 1)

    const int q = lane >> 4;             // k-chunk 0..3
    int cbuf = 0;

    for (int t = 0; t < nt; ++t) {
        if (t + 1 < nt) { asm volatile("s_waitcnt vmcnt(2)" ::: "memory"); }
        else            { asm volatile("s_waitcnt vmcnt(0)" ::: "memory"); }
        __builtin_amdgcn_s_barrier();
        asm volatile("" ::: "memory");
        __builtin_amdgcn_sched_barrier(0);
        if (t + 2 < nt) { int nb = cbuf + 2; if (nb >= 3) nb -= 3; STG(t + 2, nb) }

        bf16x8_t a[2], b[4];
        #pragma unroll
        for (int i = 0; i < 2; ++i) {
            int ra = wr * 32 + i * 16 + (lane & 15);
            a[i] = *(const bf16x8_t*)&As[cbuf][ra * 32 + ((q ^ (ra & 3)) << 3)];
        }
        #pragma unroll
        for (int j = 0; j < 4; ++j) {
            int rb = wc * 64 + j * 16 + (lane & 15);
            b[j] = *(const bf16x8_t*)&Bs[cbuf][rb * 32 + ((q ^ (rb & 3)) << 3)];
        }
        #pragma unroll
        for (int i = 0; i < 2; ++i)
            #pragma unroll
            for (int j = 0; j < 4; ++j)
                acc[i][j] = __builtin_amdgcn_mfma_f32_16x16x32_bf16(a[i], b[j], acc[i][j], 0, 0, 0);
        ++cbuf; if (cbuf >= 3) cbuf = 0;
    }
#undef STG

    float*    Cf  = (float*)Cv + bz * sC;
    ushort_t* Cb  = (ushort_t*)Cv + bz * sC;
    const ushort_t* R = Resb ? Resb + bz * sRes : nullptr;

    #pragma unroll
    for (int i = 0; i < 2; ++i) {
        #pragma unroll
        for (int j = 0; j < 4; ++j) {
            #pragma unroll
            for (int r = 0; r < 4; ++r) {
                int gm = m0 + wr * 32 + i * 16 + (lane >> 4) * 4 + r;
                int gn = n0 + wc * 64 + j * 16 + (lane & 15);
                float v = acc[i][j][r];
                long idx = (long)gm * ldc + gn;
                if (EPI == ME_F32)               Cf[idx] = v;
                else if (EPI == ME_BF16)         Cb[idx] = f2b(v);
                else if (EPI == ME_BIASCOL_BF16) Cb[idx] = f2b(v + bias[gn]);
                else if (EPI == ME_BIASCOL_ACCB16) Cb[idx] = f2b(b2f(Cb[idx]) + v + bias[gn]);
                else if (EPI == ME_GELU_BF16)    Cb[idx] = f2b(gelu_fast(v));
                else if (EPI == ME_RESB_BF16)    Cb[idx] = f2b(v + b2f(R[(long)gm * ldres + gn]));
            }
        }
    }
}

// ---------------- 64x64 GEMM, 4 waves, 3-buf, swizzled ---------------------
template<int EPI>
__global__ __launch_bounds__(256)
void sgemm_k(const ushort_t* __restrict__ A, const ushort_t* __restrict__ B,
             const float* __restrict__ bias, void* __restrict__ Cv,
             int M, int N, int K, int ldc,
             long sA, long sB, long sC)
{
    const int gx = gridDim.x, gy = gridDim.y;
    const int nwg = gx * gy * gridDim.z;
    const int lin = (blockIdx.z * gy + blockIdx.y) * gx + blockIdx.x;
    const int cpx = nwg >> 3;
    const int swz = (nwg & 7) ? lin : ((lin & 7) * cpx + (lin >> 3));
    const int bx = swz % gx;
    const int t2 = swz / gx;
    const int by = t2 % gy;
    const int bz = t2 / gy;

    A += bz * sA;
    B += bz * sB;
    const int m0 = by * 64, n0 = bx * 64;

    __shared__ __align__(16) ushort_t As[3][2048];
    __shared__ __align__(16) ushort_t Bs[3][2048];

    const int tid = threadIdx.x;
    const int wave = tid >> 6, lane = tid & 63;
    const int wr = wave >> 1, wc = wave & 1;

    f32x4_t acc[2][2] = {};

    const int skof = (((tid & 3) ^ ((tid >> 2) & 3)) << 3);
    const int srow = tid >> 2;

    const ushort_t* ga = A + (long)(m0 + srow) * K + skof;
    const ushort_t* gb = B + (long)(n0 + srow) * K + skof;
    const int nt = K >> 5;

#define STG(s, bidx) { const long ko = (long)(s) << 5; \
    __builtin_amdgcn_global_load_lds(GCAST(ga + ko), LCAST(As[bidx] + wave * 512), 16, 0, 0); \
    __builtin_amdgcn_global_load_lds(GCAST(gb + ko), LCAST(Bs[bidx] + wave * 512), 16, 0, 0); }

    STG(0, 0)
    STG(1, 1)

    const int q = lane >> 4;
    int cbuf = 0;

    for (int t = 0; t < nt; ++t) {
        if (t + 1 < nt) { asm volatile("s_waitcnt vmcnt(2)" ::: "memory"); }
        else            { asm volatile("s_waitcnt vmcnt(0)" ::: "memory"); }
        __builtin_amdgcn_s_barrier();
        asm volatile("" ::: "memory");
        __builtin_amdgcn_sched_barrier(0);
        if (t + 2 < nt) { int nb = cbuf + 2; if (nb >= 3) nb -= 3; STG(t + 2, nb) }

        bf16x8_t a[2], b[2];
        #pragma unroll
        for (int i = 0; i < 2; ++i) {
            int ra = wr * 32 + i * 16 + (lane & 15);
            a[i] = *(const bf16x8_t*)&As[cbuf][ra * 32 + ((q ^ (ra & 3)) << 3)];
        }
        #pragma unroll
        for (int j = 0; j < 2; ++j) {
            int rb = wc * 32 + j * 16 + (lane & 15);
            b[j] = *(const bf16x8_t*)&Bs[cbuf][rb * 32 + ((q ^ (rb & 3)) << 3)];
        }
        #pragma unroll
        for (int i = 0; i < 2; ++i)
            #pragma unroll
            for (int j = 0; j < 2; ++j)
                acc[i][j] = __builtin_amdgcn_mfma_f32_16x16x32_bf16(a[i], b[j], acc[i][j], 0, 0, 0);
        ++cbuf; if (cbuf >= 3) cbuf = 0;
    }
#undef STG

    float*    Cf = (float*)Cv + bz * sC;
    ushort_t* Cb = (ushort_t*)Cv + bz * sC;

    #pragma unroll
    for (int i = 0; i < 2; ++i) {
        #pragma unroll
        for (int j = 0; j < 2; ++j) {
            #pragma unroll
            for (int r = 0; r < 4; ++r) {
                int gm = m0 + wr * 32 + i * 16 + (lane >> 4) * 4 + r;
                int gn = n0 + wc * 32 + j * 16 + (lane & 15);
                float v = acc[i][j][r];
                long idx = (long)gm * ldc + gn;
                if (EPI == ME_F32)               Cf[idx] = v;
                else if (EPI == ME_BF16)         Cb[idx] = f2b(v);
                else if (EPI == ME_DCBIAS_BF16)  Cb[idx] = f2b(v + (gn == 0 ? 512.f * bias[gm] : 0.f));
                else if (EPI == ME_TREND) { if (gm < 96) Cf[idx] = v + bias[gm]; }
            }
        }
    }
}

// -------- batched complex mode-mix MFMA (per h,m), swizzled LDS ------------
__global__ __launch_bounds__(256)
void fmix_k(const ushort_t* __restrict__ A2, const ushort_t* __restrict__ B2,
            ushort_t* __restrict__ OS)
{
    const int hm = blockIdx.x;
    const int h = hm >> 6, m = hm & 63;
    __shared__ __align__(16) ushort_t As[32 * 128];
    __shared__ __align__(16) ushort_t Bs[128 * 128];

    const int tid = threadIdx.x;
    const int w = tid >> 6, lane = tid & 63;

    const ushort_t* Ag = A2 + (long)hm * 4096;
    const ushort_t* Bg = B2 + (long)hm * 16384;
    #pragma unroll
    for (int r = 0; r < 2; ++r) {
        int rowA = w * 8 + r * 4 + (lane >> 4);
        const ushort_t* src = Ag + rowA * 128 + (((lane & 15) ^ (rowA & 15)) << 3);
        __builtin_amdgcn_global_load_lds(GCAST(src), LCAST(As + w * 1024 + r * 512), 16, 0, 0);
    }
    #pragma unroll
    for (int r = 0; r < 8; ++r) {
        int rowB = w * 32 + r * 4 + (lane >> 4);
        const ushort_t* src = Bg + rowB * 128 + (((lane & 15) ^ (rowB & 15)) << 3);
        __builtin_amdgcn_global_load_lds(GCAST(src), LCAST(Bs + w * 4096 + r * 512), 16, 0, 0);
    }
    __syncthreads();

    f32x4_t acc[2][2] = {};
    #pragma unroll
    for (int kk = 0; kk < 4; ++kk) {
        const int cq = kk * 4 + (lane >> 4);
        bf16x8_t a[2], b[2];
        #pragma unroll
        for (int i = 0; i < 2; ++i) {
            int ra = i * 16 + (lane & 15);
            a[i] = *(const bf16x8_t*)&As[ra * 128 + ((cq ^ (ra & 15)) << 3)];
        }
        #pragma unroll
        for (int j = 0; j < 2; ++j) {
            int rb = w * 32 + j * 16 + (lane & 15);
            b[j] = *(const bf16x8_t*)&Bs[rb * 128 + ((cq ^ (rb & 15)) << 3)];
        }
        #pragma unroll
        for (int i = 0; i < 2; ++i)
            #pragma unroll
            for (int j = 0; j < 2; ++j)
                acc[i][j] = __builtin_amdgcn_mfma_f32_16x16x32_bf16(a[i], b[j], acc[i][j], 0, 0, 0);
    }

    #pragma unroll
    for (int i = 0; i < 2; ++i) {
        #pragma unroll
        for (int j = 0; j < 2; ++j) {
            #pragma unroll
            for (int r = 0; r < 4; ++r) {
                int b = i * 16 + (lane >> 4) * 4 + r;
                int n2 = w * 32 + j * 16 + (lane & 15);
                int o = n2 & 63, ri = n2 >> 6;
                OS[((long)b * 512 + h * 64 + o) * 128 + ri * 64 + m] = f2b(acc[i][j][r]);
            }
        }
    }
}

// B2 prep: block per (h,o). Fr/Fi [h][i][o][m] f32 -> B2[h][m][n2][k2] bf16
__global__ __launch_bounds__(256)
void bprep_k(const float* __restrict__ FR, const float* __restrict__ FI,
             ushort_t* __restrict__ B2)
{
    const int bx = blockIdx.x;
    const int h = bx >> 6, o = bx & 63;
    __shared__ float fr_s[64][65];
    __shared__ float fi_s[64][65];
    for (int e = threadIdx.x; e < 4096; e += 256) {
        int i = e >> 6, m = e & 63;
        long src = ((long)(h * 64 + i) * 64 + o) * 64 + m;
        fr_s[i][m] = FR[src];
        fi_s[i][m] = FI[src];
    }
    __syncthreads();
    const int m = threadIdx.x & 63;
    const int kq = threadIdx.x >> 6;
    ushort_t* b0 = B2 + ((long)(h * 64 + m) * 128 + o) * 128;
    ushort_t* b1 = B2 + ((long)(h * 64 + m) * 128 + o + 64) * 128;
    for (int kk = 0; kk < 32; ++kk) {
        int k2 = kq * 32 + kk;
        int ik = k2 & 63, hi = k2 >> 6;
        float fr = fr_s[ik][m], fi = fi_s[ik][m];
        b0[k2] = f2b(hi ? -fi : fr);
        b1[k2] = f2b(hi ?  fr : fi);
    }
}

// A2 prep: block per (b,h). XFTb [b][c=h*64+i][mp] bf16 -> A2[h][m][b][k2] bf16
__global__ __launch_bounds__(256)
void aprep_k(const ushort_t* __restrict__ XFTb, ushort_t* __restrict__ A2)
{
    const int bx = blockIdx.x;
    const int b = bx >> 3, h = bx & 7;
    __shared__ ushort_t xs[64][130];
    for (int e = threadIdx.x; e < 8192; e += 256) {
        int i = e >> 7, mp = e & 127;
        xs[i][mp] = XFTb[((long)b * 512 + h * 64 + i) * 128 + mp];
    }
    __syncthreads();
    const int m = threadIdx.x & 63;
    const int kq = threadIdx.x >> 6;
    ushort_t* dst = A2 + ((long)(h * 64 + m) * 32 + b) * 128;
    for (int kk = 0; kk < 32; ++kk) {
        int k2 = kq * 32 + kk;
        int i = k2 & 63, ri = k2 >> 6;
        dst[k2] = xs[i][ri * 64 + m];
    }
}

// ------- start decomp (k=25), f32 in -> TRANSPOSED bf16 seasonal/trend -----
__global__ __launch_bounds__(256)
void decomp2t_k(const float* __restrict__ X, ushort_t* __restrict__ SbT,
                ushort_t* __restrict__ TrbT)
{
    const int id = blockIdx.x;
    const int ch = id & 1, rc = (id >> 1) & 31, b = id >> 6;
    const int c = ch * 256 + threadIdx.x;
    const int r0 = rc * 16;
    const long base = ((long)b << 18) + c;
    float s = 0.f;
    #pragma unroll
    for (int j = -12; j <= 12; ++j) {
        int rr = r0 + j; rr = rr < 0 ? 0 : (rr > 511 ? 511 : rr);
        s += X[base + ((long)rr << 9)];
    }
    u16x8_t sv0, sv1, tv0, tv1;
    for (int rr = 0; rr < 16; ++rr) {
        int r = r0 + rr;
        float mean = s * (1.f / 25.f);
        float x = X[base + ((long)r << 9)];
        if (rr < 8) { sv0[rr] = f2b(x - mean); tv0[rr] = f2b(mean); }
        else        { sv1[rr - 8] = f2b(x - mean); tv1[rr - 8] = f2b(mean); }
        int rp = r + 13; rp = rp > 511 ? 511 : rp;
        int rm = r - 12; rm = rm < 0 ? 0 : rm;
        s += X[base + ((long)rp << 9)] - X[base + ((long)rm << 9)];
    }
    long obase = (long)b * 262144 + (long)c * 512 + r0;
    *(u16x8_t*)&SbT[obase] = sv0;  *(u16x8_t*)&SbT[obase + 8] = sv1;
    *(u16x8_t*)&TrbT[obase] = tv0; *(u16x8_t*)&TrbT[obase + 8] = tv1;
}

// ------- sliding-window series_decomp (k=25), bf16 in/out, vectorized ------
__global__ __launch_bounds__(256)
void decomp2v_k(const ushort_t* __restrict__ Xb, ushort_t* __restrict__ Sb)
{
    const int id = blockIdx.x;
    const int b = id >> 4, rc = id & 15;
    const int c0 = (threadIdx.x & 63) * 8;
    const int rsub = threadIdx.x >> 6;
    const int r0 = rc * 32 + rsub * 8;
    const ushort_t* base = Xb + ((long)b << 18) + c0;
    ushort_t* obase = Sb + ((long)b << 18) + c0;

    float s[8] = {};
    #pragma unroll
    for (int j = -12; j <= 12; ++j) {
        int rr = r0 + j; rr = rr < 0 ? 0 : (rr > 511 ? 511 : rr);
        u16x8_t v = *(const u16x8_t*)(base + ((long)rr << 9));
        #pragma unroll
        for (int k = 0; k < 8; ++k) s[k] += b2f(v[k]);
    }
    for (int rr = 0; rr < 8; ++rr) {
        int r = r0 + rr;
        u16x8_t xv = *(const u16x8_t*)(base + ((long)r << 9));
        u16x8_t ov;
        #pragma unroll
        for (int k = 0; k < 8; ++k) ov[k] = f2b(b2f(xv[k]) - s[k] * (1.f / 25.f));
        *(u16x8_t*)(obase + ((long)r << 9)) = ov;
        int rp = r + 13; rp = rp > 511 ? 511 : rp;
        int rm = r - 12; rm = rm < 0 ? 0 : rm;
        u16x8_t vp = *(const u16x8_t*)(base + ((long)rp << 9));
        u16x8_t vm = *(const u16x8_t*)(base + ((long)rm << 9));
        #pragma unroll
        for (int k = 0; k < 8; ++k) s[k] += b2f(vp[k]) - b2f(vm[k]);
    }
}

// ----------------------- bf16 DFT tables -----------------------------------
__global__ __launch_bounds__(256)
void init_tables_k(ushort_t* __restrict__ TFb, ushort_t* __restrict__ TI2b)
{
    int t = blockIdx.x * 256 + threadIdx.x;   // 0..131071
    const float w = 6.283185307179586f / 512.f;
    if (t < 65536) {
        int mp = t >> 9, n = t & 511;
        int m = mp & 63;
        float ang = ((m * n) & 511) * w;
        TFb[t] = f2b((mp < 64) ? cosf(ang) : -sinf(ang));
    } else {
        int u = t - 65536;
        int mp = u >> 9, n = u & 511;
        int m = mp & 63;
        float ang = ((m * n) & 511) * w;
        float v;
        if (mp < 64) v = (m == 0) ? (1.f / 512.f) : (2.f / 512.f) * cosf(ang);
        else         v = (m == 0) ? 0.f : -(2.f / 512.f) * sinf(ang);
        TI2b[u] = f2b(v);
    }
}

// ----------------------- fp32 -> bf16 convert (weights) --------------------
__global__ __launch_bounds__(256)
void f2b_k(const float* __restrict__ X, ushort_t* __restrict__ Y, long n)
{
    long i = ((long)blockIdx.x * 256 + threadIdx.x) * 8;
    if (i >= n) return;
    const float4* xp = (const float4*)(X + i);
    float4 v0 = xp[0], v1 = xp[1];
    u16x8_t o;
    o[0] = f2b(v0.x); o[1] = f2b(v0.y); o[2] = f2b(v0.z); o[3] = f2b(v0.w);
    o[4] = f2b(v1.x); o[5] = f2b(v1.y); o[6] = f2b(v1.z); o[7] = f2b(v1.w);
    *(u16x8_t*)(Y + i) = o;
}

// ----------------- fp32 [R,C] -> bf16 transposed [C,R] ---------------------
__global__ __launch_bounds__(256)
void trans_b_k(const float* __restrict__ X, ushort_t* __restrict__ Y,
               int R, int C, long sX, long sY)
{
    __shared__ float t[32][33];
    X += (long)blockIdx.z * sX;
    Y += (long)blockIdx.z * sY;
    int r0 = blockIdx.y * 32, c0 = blockIdx.x * 32;
    int tx = threadIdx.x & 31, ty = threadIdx.x >> 5;
    #pragma unroll
    for (int i = ty; i < 32; i += 8)
        t[i][tx] = X[(long)(r0 + i) * C + c0 + tx];
    __syncthreads();
    #pragma unroll
    for (int i = ty; i < 32; i += 8)
        Y[(long)(c0 + i) * R + r0 + tx] = f2b(t[tx][i]);
}

// ----------------- bf16 [R,C] -> bf16 transposed [C,R] ---------------------
__global__ __launch_bounds__(256)
void trans_bb_k(const ushort_t* __restrict__ X, ushort_t* __restrict__ Y,
                int R, int C, long sX, long sY)
{
    __shared__ ushort_t t[32][34];
    X += (long)blockIdx.z * sX;
    Y += (long)blockIdx.z * sY;
    int r0 = blockIdx.y * 32, c0 = blockIdx.x * 32;
    int tx = threadIdx.x & 31, ty = threadIdx.x >> 5;
    #pragma unroll
    for (int i = ty; i < 32; i += 8)
        t[i][tx] = X[(long)(r0 + i) * C + c0 + tx];
    __syncthreads();
    #pragma unroll
    for (int i = ty; i < 32; i += 8)
        Y[(long)(c0 + i) * R + r0 + tx] = t[tx][i];
}

// --------------------- layernorm (bf16 in/out, f32 math) -------------------
__global__ __launch_bounds__(256)
void ln_rows_bb_k(const ushort_t* __restrict__ Xb, const float* __restrict__ g,
                  const float* __restrict__ bta, ushort_t* __restrict__ Yb)
{
    int wave = threadIdx.x >> 6, lane = threadIdx.x & 63;
    long row = (long)blockIdx.x * 4 + wave;
    const ushort_t* x = Xb + row * 512 + lane * 8;
    u16x8_t v = *(const u16x8_t*)x;
    float f[8];
    float s = 0.f, ss = 0.f;
    #pragma unroll
    for (int j = 0; j < 8; ++j) { f[j] = b2f(v[j]); s += f[j]; ss += f[j] * f[j]; }
    #pragma unroll
    for (int o = 32; o; o >>= 1) { s += __shfl_xor(s, o); ss += __shfl_xor(ss, o); }
    float mu = s * (1.f / 512.f);
    float var = ss * (1.f / 512.f) - mu * mu;
    float inv = rsqrtf(var + 1e-5f);
    u16x8_t ov;
    #pragma unroll
    for (int j = 0; j < 8; ++j)
        ov[j] = f2b((f[j] - mu) * inv * g[lane * 8 + j] + bta[lane * 8 + j]);
    *(u16x8_t*)(Yb + row * 512 + lane * 8) = ov;
}

// subtract per-(b,d) seq-mean, bf16 in/out (4 waves split the t-loop)
__global__ __launch_bounds__(256)
void colmean_bb_k(const ushort_t* __restrict__ Y, ushort_t* __restrict__ O)
{
    __shared__ float ps[4][64];
    int b = blockIdx.x, dg = blockIdx.y;
    int wave = threadIdx.x >> 6, lane = threadIdx.x & 63;
    int d = dg * 64 + lane;
    long base = (long)b * 262144 + d;
    float s = 0.f;
    for (int t = wave * 128; t < wave * 128 + 128; ++t)
        s += b2f(Y[base + ((long)t << 9)]);
    ps[wave][lane] = s;
    __syncthreads();
    float mean = (ps[0][lane] + ps[1][lane] + ps[2][lane] + ps[3][lane]) * (1.f / 512.f);
    for (int t = wave * 128; t < wave * 128 + 128; ++t)
        O[base + ((long)t << 9)] = f2b(b2f(Y[base + ((long)t << 9)]) - mean);
}

// head transpose-add: out[b,p,t] += Thead[(b*512+t)*128+p] + b_head[p]
__global__ __launch_bounds__(256)
void headadd_k(const float* __restrict__ Th, const float* __restrict__ bh,
               float* __restrict__ out)
{
    const int id = blockIdx.x;          // b*16 + tc
    const int b = id >> 4, t0 = (id & 15) * 32;
    __shared__ float tile[32][100];
    for (int e = threadIdx.x; e < 32 * 96; e += 256) {
        int tl = e / 96, p = e - tl * 96;
        tile[tl][p] = Th[((long)(b * 512 + t0 + tl)) * 128 + p];
    }
    __syncthreads();
    for (int e = threadIdx.x; e < 96 * 32; e += 256) {
        int p = e >> 5, tl = e & 31;
        out[(long)b * 49152 + p * 512 + t0 + tl] += tile[tl][p] + bh[p];
    }
}

// ===========================================================================
extern "C" void kernel_launch(void* const* d_in, const int* in_sizes, int n_in,
                              void* d_out, int out_size, void* d_ws, size_t ws_size,
                              hipStream_t stream)
{
    const float* x_enc   = (const float*)d_in[0];
    const float* W_trend = (const float*)d_in[4];
    const float* b_trend = (const float*)d_in[5];
    const float* W_emb   = (const float*)d_in[6];
    const float* b_emb   = (const float*)d_in[7];
    const float* Wq      = (const float*)d_in[8];
    const float* bq      = (const float*)d_in[9];
    const float* fw_r    = (const float*)d_in[14];
    const float* fw_i    = (const float*)d_in[15];
    const float* Wo      = (const float*)d_in[16];
    const float* bo      = (const float*)d_in[17];
    const float* W1      = (const float*)d_in[18];
    const float* W2      = (const float*)d_in[19];
    const float* ln_g    = (const float*)d_in[20];
    const float* ln_b    = (const float*)d_in[21];
    const float* W_head  = (const float*)d_in[22];
    const float* b_head  = (const float*)d_in[23];
    float* out = (float*)d_out;
    float* ws  = (float*)d_ws;

    const long F = 8388608;
    float* G    = ws;
    ushort_t* xw  = (ushort_t*)(ws + 3 * F);           // encoder state bf16
    ushort_t* xs  = (ushort_t*)(ws + 4 * F);           // seasonal / FFN residual
    ushort_t* T1b = xs + 8388608;                      // FFN out / LN out
    ushort_t* qT  = (ushort_t*)(ws + 5 * F);           // seasT at start

    ushort_t* trendT = (ushort_t*)G;
    ushort_t* XFTb  = (ushort_t*)G;                    // [0,4MB)
    ushort_t* Yb    = (ushort_t*)(G + 1048576);        // [4,8MB)
    ushort_t* A2    = (ushort_t*)(G + 2097152);        // [8,12MB)
    ushort_t* OSELb = (ushort_t*)(G + 3145728);        // [12,16MB)
    ushort_t* xbT   = (ushort_t*)(G + 4194304);        // [16,32MB)
    ushort_t* B2    = (ushort_t*)(G + 8388608);        // [32,48MB)
    float*    Thead = G;
    ushort_t* gb    = (ushort_t*)G;                    // FFN-phase 64MB

    ushort_t* WembT  = (ushort_t*)(ws + 6 * F);        // 262144
    ushort_t* WTq2   = WembT + 262144;                 // 2 x 262144
    ushort_t* WTo2   = WTq2 + 524288;                  // 2 x 262144
    ushort_t* W1b2   = WTo2 + 524288;                  // 2 x 1048576
    ushort_t* W2b2   = W1b2 + 2097152;                 // 2 x 1048576
    ushort_t* TFb    = W2b2 + 2097152;                 // 65536
    ushort_t* TI2b   = TFb + 65536;                    // 65536
    ushort_t* WtT    = TI2b + 65536;
    ushort_t* WheadT = WtT + 65536;
    ushort_t* TIWob2 = WheadT + 65536;                 // 2 x 65536

    dim3 blk(256), blk5(512);

    init_tables_k<<<dim3(512), blk, 0, stream>>>(TFb, TI2b);

    // decomp(x_enc) -> TRANSPOSED seasonal (qT) + trend (G)
    decomp2t_k<<<dim3(2048), blk, 0, stream>>>(x_enc, qT, trendT);

    // hoisted weight prep (both layers batched)
    trans_b_k<<<dim3(3, 16, 1), blk, 0, stream>>>(W_trend, WtT, 512, 96, 0L, 0L);
    trans_b_k<<<dim3(3, 16, 1), blk, 0, stream>>>(W_head, WheadT, 512, 96, 0L, 0L);
    trans_b_k<<<dim3(16, 16, 1), blk, 0, stream>>>(W_emb, WembT, 512, 512, 0L, 0L);
    trans_b_k<<<dim3(16, 16, 2), blk, 0, stream>>>(Wq, WTq2, 512, 512, 262144L, 262144L);
    trans_b_k<<<dim3(16, 16, 2), blk, 0, stream>>>(Wo, WTo2, 512, 512, 262144L, 262144L);
    f2b_k<<<dim3(1024), blk, 0, stream>>>(W1, W1b2, 2097152L);
    f2b_k<<<dim3(1024), blk, 0, stream>>>(W2, W2b2, 2097152L);
    sgemm_k<ME_BF16><<<dim3(2, 8, 2), blk, 0, stream>>>(
        WTo2, TI2b, nullptr, TIWob2,
        512, 128, 512, 128, 262144L, 0L, 65536L);

    // trend head GEMM -> out
    sgemm_k<ME_TREND><<<dim3(8, 2, 32), blk, 0, stream>>>(
        WtT, trendT, b_trend, out,
        128, 512, 512, 512, 0L, 262144L, 49152L);

    // embedding -> xw bf16
    mgemm_k<ME_BIASCOL_BF16><<<dim3(4, 4, 32), blk5, 0, stream>>>(
        qT, WembT, b_emb, nullptr, xw,
        512, 512, 512, 512, 0, 262144L, 0L, 262144L, 0L);

    for (int l = 0; l < 2; ++l) {
        const float* bq_l = bq + (long)l * 512;
        const float* bo_l = bo + (long)l * 512;
        const float* fr_l = fw_r + (long)l * 2097152;
        const float* fi_l = fw_i + (long)l * 2097152;
        const ushort_t* WTq_l   = WTq2 + (long)l * 262144;
        const ushort_t* W1b_l   = W1b2 + (long)l * 1048576;
        const ushort_t* W2b_l   = W2b2 + (long)l * 1048576;
        const ushort_t* TIWob_l = TIWob2 + (long)l * 65536;

        bprep_k<<<dim3(512), blk, 0, stream>>>(fr_l, fi_l, B2);

        // xbT[b,d,n] = xw[b,n,d]^T
        trans_bb_k<<<dim3(16, 16, 32), blk, 0, stream>>>(xw, xbT, 512, 512, 262144L, 262144L);

        // G1: Yb[b,mp,d] = sum_n TFb[mp,n] * xbT[b,d,n]
        sgemm_k<ME_BF16><<<dim3(8, 2, 32), blk, 0, stream>>>(
            TFb, xbT, nullptr, Yb,
            128, 512, 512, 512, 0L, 262144L, 65536L);

        // G2: XFTb[b,c,mp] = sum_d WTq[c,d] * Yb[b,mp,d]  (+512*bq[c] at mp=0)
        sgemm_k<ME_DCBIAS_BF16><<<dim3(2, 8, 32), blk, 0, stream>>>(
            WTq_l, Yb, bq_l, XFTb,
            512, 128, 512, 128, 0L, 65536L, 65536L);

        aprep_k<<<dim3(256), blk, 0, stream>>>(XFTb, A2);
        fmix_k<<<dim3(512), blk, 0, stream>>>(A2, B2, OSELb);

        // xw += OSEL . TIWo^T + bo   (bf16 RMW)
        mgemm_k<ME_BIASCOL_ACCB16><<<dim3(4, 128, 1), blk5, 0, stream>>>(
            OSELb, TIWob_l, bo_l, nullptr, xw,
            16384, 512, 128, 512, 0, 0L, 0L, 0L, 0L);

        // decomp (bf16, vectorized) -> xs (FFN input + FFN2 residual)
        decomp2v_k<<<dim3(512), blk, 0, stream>>>(xw, xs);

        // FFN, full M=16384
        mgemm_k<ME_GELU_BF16><<<dim3(16, 128, 1), blk5, 0, stream>>>(
            xs, W1b_l, nullptr, nullptr, gb,
            16384, 2048, 512, 2048, 0, 0L, 0L, 0L, 0L);
        mgemm_k<ME_RESB_BF16><<<dim3(4, 128, 1), blk5, 0, stream>>>(
            gb, W2b_l, nullptr, xs, T1b,
            16384, 512, 2048, 512, 512, 0L, 0L, 0L, 0L);

        // decomp (bf16, vectorized) -> xw (next layer state / LN input)
        decomp2v_k<<<dim3(512), blk, 0, stream>>>(T1b, xw);
    }

    // my_layernorm (bf16): rows -> T1b, colmean-subtract -> xs
    ln_rows_bb_k<<<dim3(4096), blk, 0, stream>>>(xw, ln_g, ln_b, T1b);
    colmean_bb_k<<<dim3(32, 8), blk, 0, stream>>>(T1b, xs);

    // head
    sgemm_k<ME_F32><<<dim3(2, 256, 1), blk, 0, stream>>>(
        xs, WheadT, nullptr, Thead,
        16384, 128, 512, 128, 0L, 0L, 0L);

    headadd_k<<<dim3(512), blk, 0, stream>>>(Thead, b_head, out);
}